// Round 13
// baseline (494.633 us; speedup 1.0000x reference)
//
#include <hip/hip_runtime.h>
#include <hip/hip_bf16.h>

#define Bb 2
#define Hh 16
#define Ll 2048
#define Dd 64
#define OUT_ELEMS (Bb*Hh*Ll*Dd)
#define BHL (Bb*Hh*Ll)

typedef __attribute__((ext_vector_type(8))) short bf16x8;
typedef __attribute__((ext_vector_type(4))) float f32x4;
typedef __attribute__((ext_vector_type(4))) int i32x4;
typedef __attribute__((ext_vector_type(2))) unsigned int u32x2;

__device__ __forceinline__ unsigned int pk2(float a, float b) {
    unsigned int r;
    asm("v_cvt_pk_bf16_f32 %0, %1, %2" : "=v"(r) : "v"(a), "v"(b));
    return r;
}
__device__ __forceinline__ float bf2f(short s) {
    union { float f; unsigned u; } c;
    c.u = ((unsigned)(unsigned short)s) << 16;
    return c.f;
}
// raw barrier: does NOT drain vmcnt -> prefetched loads stay in flight (T4)
__device__ __forceinline__ void bar() {
    asm volatile("s_waitcnt lgkmcnt(0)" ::: "memory");
    __builtin_amdgcn_s_barrier();
}
// XOR-swizzled LDS byte offset for 128B rows (kills ds_read_b128 conflicts)
__device__ __forceinline__ int swz(int row, int colByte) {
    return row * 128 + (colByte ^ ((row & 7) << 4));
}

// ===== kernel A: QK^T -> exp -> {Ex bf16, rowsum partials, O_part via PV} =====
__global__ __launch_bounds__(256)
void attn_main(const float* __restrict__ Q, const float* __restrict__ K,
               const float* __restrict__ V, const int* __restrict__ M,
               const float* __restrict__ Bi, float* __restrict__ ws,
               float* __restrict__ out)
{
    __shared__ char Ks[2][64 * 128];
    __shared__ char VTs[2][64 * 128];
    __shared__ char Ps[64 * 128];

    const int bid = blockIdx.x;          // 4096 blocks
    const int ks = bid & 3;
    const int b  = (bid >> 2) & 1;
    const int qt = (bid >> 3) & 31;
    const int h  = bid >> 8;
    const int q0 = qt * 64;
    const int kb = ks * 512;             // 8 tiles of 64

    const int tid  = threadIdx.x;
    const int w    = tid >> 6;
    const int lane = tid & 63;
    const int g    = lane >> 4;
    const int c16  = lane & 15;
    const int qr   = w * 16 + c16;

    const float* Qp = Q + ((size_t)(b * Hh + h) * Ll + q0) * Dd;
    const float* Kp = K + (size_t)(b * Hh + h) * Ll * Dd;
    const float* Vp = V + (size_t)(b * Hh + h) * Ll * Dd;
    const int*   mrow = M  + (size_t)b * Ll * Ll + ((size_t)q0 + qr) * Ll;
    const float* brow = Bi + (size_t)h * Ll * Ll + ((size_t)q0 + qr) * Ll;
    unsigned short* srow = (unsigned short*)(ws + 4 * (size_t)BHL)
                         + ((size_t)(b * Hh + h) * Ll + q0 + qr) * (size_t)Ll;
    // unnormalized O partials live in the (later overwritten) P region of out
    float* op = out + OUT_ELEMS + (size_t)ks * OUT_ELEMS
              + ((size_t)(b * Hh + h) * Ll + q0) * Dd;

    bf16x8 qf[2];
    {
        const float* qrow = Qp + qr * Dd;
#pragma unroll
        for (int kk = 0; kk < 2; ++kk) {
            f32x4 a = *(const f32x4*)(qrow + kk * 32 + g * 8);
            f32x4 c = *(const f32x4*)(qrow + kk * 32 + g * 8 + 4);
            union { bf16x8 v; unsigned int u[4]; } cvt;
            cvt.u[0] = pk2(a[0], a[1]); cvt.u[1] = pk2(a[2], a[3]);
            cvt.u[2] = pk2(c[0], c[1]); cvt.u[3] = pk2(c[2], c[3]);
            qf[kk] = cvt.v;
        }
    }

    float4 kreg[4];
    float  vreg[16];
    i32x4  m4[4];
    f32x4  b4[4];
    const int r0 = tid >> 4, d0 = (tid & 15) * 4;

    auto issueK = [&](int k0) {
#pragma unroll
        for (int rep = 0; rep < 4; ++rep)
            kreg[rep] = *(const float4*)(Kp + (size_t)(k0 + r0 + rep * 16) * Dd + d0);
    };
    auto writeK = [&](char* buf) {
#pragma unroll
        for (int rep = 0; rep < 4; ++rep) {
            u32x2 u = { pk2(kreg[rep].x, kreg[rep].y), pk2(kreg[rep].z, kreg[rep].w) };
            *(u32x2*)(buf + swz(r0 + rep * 16, d0 * 2)) = u;
        }
    };
    auto issueV = [&](int k0) {
#pragma unroll
        for (int r = 0; r < 4; ++r)
#pragma unroll
            for (int i = 0; i < 4; ++i)
                vreg[r * 4 + i] = Vp[(size_t)(k0 + w * 16 + r * 4 + i) * Dd + lane];
    };
    auto writeV = [&](char* buf) {       // transposed: buf[d][k]
#pragma unroll
        for (int r = 0; r < 4; ++r) {
            u32x2 u = { pk2(vreg[r * 4 + 0], vreg[r * 4 + 1]),
                        pk2(vreg[r * 4 + 2], vreg[r * 4 + 3]) };
            *(u32x2*)(buf + swz(lane, (w * 16 + r * 4) * 2)) = u;
        }
    };
    auto issueMB = [&](int k0) {
#pragma unroll
        for (int ct = 0; ct < 4; ++ct) {
            m4[ct] = *(const i32x4*)(mrow + k0 + ct * 16 + g * 4);
            b4[ct] = *(const f32x4*)(brow + k0 + ct * 16 + g * 4);
        }
    };

    issueK(kb);
    issueMB(kb);
    issueV(kb);
    writeK(Ks[0]);
    writeV(VTs[0]);
    issueK(kb + 64);
    issueV(kb + 64);
    bar();

    float rsv[4] = {0.f, 0.f, 0.f, 0.f};
    f32x4 oacc[4] = {{0,0,0,0},{0,0,0,0},{0,0,0,0},{0,0,0,0}};
    for (int t = 0; t < 8; ++t) {
        // ---- QK^T (S^T fragments) ----
        f32x4 sacc[4] = {{0,0,0,0},{0,0,0,0},{0,0,0,0},{0,0,0,0}};
        __builtin_amdgcn_s_setprio(1);
#pragma unroll
        for (int kk = 0; kk < 2; ++kk)
#pragma unroll
            for (int ct = 0; ct < 4; ++ct) {
                bf16x8 af = *(const bf16x8*)(Ks[t & 1] + swz(ct * 16 + c16, kk * 64 + g * 16));
                sacc[ct] = __builtin_amdgcn_mfma_f32_16x16x32_bf16(af, qf[kk], sacc[ct], 0, 0, 0);
            }
        __builtin_amdgcn_s_setprio(0);
        // ---- mask+bias+exp -> Ps (own-wave rows) ----
#pragma unroll
        for (int ct = 0; ct < 4; ++ct) {
            f32x4 e;
#pragma unroll
            for (int r = 0; r < 4; ++r) {
                float s = m4[ct][r] == 0 ? -10000.0f
                                         : fmaf(sacc[ct][r], 0.125f, b4[ct][r]);
                e[r] = __expf(s);
                rsv[ct] += e[r];
            }
            u32x2 u = { pk2(e[0], e[1]), pk2(e[2], e[3]) };
            *(u32x2*)(Ps + swz(qr, ct * 32 + g * 8)) = u;
        }
        // ---- pa from Ps: Ex dump + PV accumulate ----
        const int kc = kb + t * 64;
        __builtin_amdgcn_s_setprio(1);
#pragma unroll
        for (int kk = 0; kk < 2; ++kk) {
            bf16x8 pa = *(const bf16x8*)(Ps + swz(qr, kk * 64 + g * 16));
            *(bf16x8*)(srow + kc + kk * 32 + g * 8) = pa;   // Ex (regular store)
#pragma unroll
            for (int dt = 0; dt < 4; ++dt) {
                bf16x8 vf = *(const bf16x8*)(VTs[t & 1] + swz(dt * 16 + c16, kk * 64 + g * 16));
                oacc[dt] = __builtin_amdgcn_mfma_f32_16x16x32_bf16(pa, vf, oacc[dt], 0, 0, 0);
            }
        }
        __builtin_amdgcn_s_setprio(0);
        // ---- stage tile t+1, issue tile t+2 ----
        writeK(Ks[(t + 1) & 1]);
        writeV(VTs[(t + 1) & 1]);
        issueK(kb + ((t + 2) & 7) * 64);     // wrap: harmless extra reads
        issueV(kb + ((t + 2) & 7) * 64);
        issueMB(kb + ((t + 1) & 7) * 64);
        bar();
    }
    float rs = (rsv[0] + rsv[1]) + (rsv[2] + rsv[3]);
    rs += __shfl_xor(rs, 16);
    rs += __shfl_xor(rs, 32);
    if (g == 0)
        ws[(size_t)ks * BHL + (size_t)(b * Hh + h) * Ll + q0 + qr] = rs;
    // unnormalized O partial for this ks chunk
#pragma unroll
    for (int dt = 0; dt < 4; ++dt)
#pragma unroll
        for (int r = 0; r < 4; ++r)
            op[(w * 16 + g * 4 + r) * Dd + dt * 16 + c16] = oacc[dt][r];
}

// ===== kernel B: O = (sum of 4 O_parts) * inv ===== (84 MB, linear)
__global__ __launch_bounds__(256)
void norm_o(const float* __restrict__ ws, float* __restrict__ out)
{
    const size_t idx = ((size_t)blockIdx.x * 256 + threadIdx.x) * 4;
    const size_t row = idx >> 6;         // Dd = 64
    float s = ws[row] + ws[(size_t)BHL + row]
            + ws[2 * (size_t)BHL + row] + ws[3 * (size_t)BHL + row];
    const float inv = 1.0f / s;
    const float* Opart = out + OUT_ELEMS;
    f32x4 o = *(const f32x4*)(Opart + idx);
    o += *(const f32x4*)(Opart + (size_t)OUT_ELEMS + idx);
    o += *(const f32x4*)(Opart + 2 * (size_t)OUT_ELEMS + idx);
    o += *(const f32x4*)(Opart + 3 * (size_t)OUT_ELEMS + idx);
    o *= inv;
    *(f32x4*)(out + idx) = o;
}

// ===== kernel C: P = bf2f(Ex) * inv ===== (805 MB, fill-like linear)
__global__ __launch_bounds__(256)
void norm_p(const float* __restrict__ ws, float* __restrict__ out)
{
    const size_t i = ((size_t)blockIdx.x * 256 + threadIdx.x) * 8;
    const size_t row = i >> 11;          // Ll = 2048
    float s = ws[row] + ws[(size_t)BHL + row]
            + ws[2 * (size_t)BHL + row] + ws[3 * (size_t)BHL + row];
    const float inv = 1.0f / s;
    const unsigned short* Ex = (const unsigned short*)(ws + 4 * (size_t)BHL);
    bf16x8 e = *(const bf16x8*)(Ex + i);
    f32x4 p0, p1;
#pragma unroll
    for (int j = 0; j < 4; ++j) {
        p0[j] = bf2f(e[j]) * inv;
        p1[j] = bf2f(e[4 + j]) * inv;
    }
    float* dst = out + OUT_ELEMS + i;
    __builtin_nontemporal_store(p0, (f32x4*)(dst));
    __builtin_nontemporal_store(p1, (f32x4*)(dst + 4));
}

extern "C" void kernel_launch(void* const* d_in, const int* in_sizes, int n_in,
                              void* d_out, int out_size, void* d_ws, size_t ws_size,
                              hipStream_t stream) {
    const float* Q  = (const float*)d_in[0];
    const float* K  = (const float*)d_in[1];
    const float* V  = (const float*)d_in[2];
    const int*   M  = (const int*)d_in[3];
    const float* Bi = (const float*)d_in[4];
    float* out = (float*)d_out;
    float* ws  = (float*)d_ws;

    // ws layout: [0, 1MB) rowsum partials (4*BHL f32); [1MB, +268MB) Ex bf16.
    // O_part slots (4*OUT_ELEMS f32 = 67MB) live in out's P region, which
    // norm_p fully overwrites afterwards (A -> B -> C stream order).
    const size_t need = 4ull * BHL * sizeof(float)
                      + (size_t)BHL * Ll * sizeof(unsigned short);
    if (ws_size >= need) {
        attn_main<<<dim3(4096),  dim3(256), 0, stream>>>(Q, K, V, M, Bi, ws, out);
        norm_o  <<<dim3(OUT_ELEMS / 1024), dim3(256), 0, stream>>>(ws, out);
        norm_p  <<<dim3((size_t)BHL * Ll / 2048), dim3(256), 0, stream>>>(ws, out);
    }
}

// Round 14
// 416.193 us; speedup vs baseline: 1.1885x; 1.1885x over previous
//
#include <hip/hip_runtime.h>
#include <hip/hip_bf16.h>

#define Bb 2
#define Hh 16
#define Ll 2048
#define Dd 64
#define OUT_ELEMS (Bb*Hh*Ll*Dd)
#define BHL (Bb*Hh*Ll)
#define TILE 4096   // one Ex tile = 64q x 64k bf16 elements

typedef __attribute__((ext_vector_type(8))) short bf16x8;
typedef __attribute__((ext_vector_type(4))) short bf16x4;
typedef __attribute__((ext_vector_type(4))) float f32x4;
typedef __attribute__((ext_vector_type(4))) int i32x4;
typedef __attribute__((ext_vector_type(2))) unsigned int u32x2;

__device__ __forceinline__ unsigned int pk2(float a, float b) {
    unsigned int r;
    asm("v_cvt_pk_bf16_f32 %0, %1, %2" : "=v"(r) : "v"(a), "v"(b));
    return r;
}
__device__ __forceinline__ float bf2f(short s) {
    union { float f; unsigned u; } c;
    c.u = ((unsigned)(unsigned short)s) << 16;
    return c.f;
}
// raw barrier: does NOT drain vmcnt -> prefetched loads stay in flight (T4)
__device__ __forceinline__ void bar() {
    asm volatile("s_waitcnt lgkmcnt(0)" ::: "memory");
    __builtin_amdgcn_s_barrier();
}
// XOR-swizzled LDS byte offset for 128B rows (kills ds_read_b128 conflicts)
__device__ __forceinline__ int swz(int row, int colByte) {
    return row * 128 + (colByte ^ ((row & 7) << 4));
}

// ===== pass 1: exp(S) -> TILED bf16 scratch + partial rowsums =====
__global__ __launch_bounds__(256)
void attn_exp(const float* __restrict__ Q, const float* __restrict__ K,
              const int* __restrict__ M, const float* __restrict__ Bi,
              float* __restrict__ ws)
{
    __shared__ char Ks[2][64 * 128];
    __shared__ char Ps[64 * 128];

    const int bid = blockIdx.x;          // 4096 blocks
    const int ks = bid & 3;
    const int b  = (bid >> 2) & 1;
    const int qt = (bid >> 3) & 31;
    const int h  = bid >> 8;
    const int q0 = qt * 64;
    const int kb = ks * 512;             // 8 tiles of 64

    const int tid  = threadIdx.x;
    const int w    = tid >> 6;
    const int lane = tid & 63;
    const int g    = lane >> 4;
    const int c16  = lane & 15;
    const int qr   = w * 16 + c16;

    const float* Qp = Q + ((size_t)(b * Hh + h) * Ll + q0) * Dd;
    const float* Kp = K + (size_t)(b * Hh + h) * Ll * Dd;
    const int*   mrow = M  + (size_t)b * Ll * Ll + ((size_t)q0 + qr) * Ll;
    const float* brow = Bi + (size_t)h * Ll * Ll + ((size_t)q0 + qr) * Ll;
    unsigned short* Exg = (unsigned short*)(ws + 4 * (size_t)BHL);
    const size_t tb0 = (((size_t)(b * Hh + h) * 32 + qt) * 32 + (kb >> 6)) * TILE;

    bf16x8 qf[2];
    {
        const float* qrow = Qp + qr * Dd;
#pragma unroll
        for (int kk = 0; kk < 2; ++kk) {
            f32x4 a = *(const f32x4*)(qrow + kk * 32 + g * 8);
            f32x4 c = *(const f32x4*)(qrow + kk * 32 + g * 8 + 4);
            union { bf16x8 v; unsigned int u[4]; } cvt;
            cvt.u[0] = pk2(a[0], a[1]); cvt.u[1] = pk2(a[2], a[3]);
            cvt.u[2] = pk2(c[0], c[1]); cvt.u[3] = pk2(c[2], c[3]);
            qf[kk] = cvt.v;
        }
    }

    float4 kreg[4];
    i32x4  m4[4];
    f32x4  b4[4];
    const int r0 = tid >> 4, d0 = (tid & 15) * 4;

    auto issueK = [&](int k0) {
#pragma unroll
        for (int rep = 0; rep < 4; ++rep)
            kreg[rep] = *(const float4*)(Kp + (size_t)(k0 + r0 + rep * 16) * Dd + d0);
    };
    auto writeK = [&](char* buf) {
#pragma unroll
        for (int rep = 0; rep < 4; ++rep) {
            u32x2 u = { pk2(kreg[rep].x, kreg[rep].y), pk2(kreg[rep].z, kreg[rep].w) };
            *(u32x2*)(buf + swz(r0 + rep * 16, d0 * 2)) = u;
        }
    };
    auto issueMB = [&](int k0) {
#pragma unroll
        for (int ct = 0; ct < 4; ++ct) {
            m4[ct] = *(const i32x4*)(mrow + k0 + ct * 16 + g * 4);
            b4[ct] = *(const f32x4*)(brow + k0 + ct * 16 + g * 4);
        }
    };

    issueK(kb);
    issueMB(kb);
    writeK(Ks[0]);
    issueK(kb + 64);
    bar();

    float rsv[4] = {0.f, 0.f, 0.f, 0.f};
    for (int t = 0; t < 8; ++t) {
        f32x4 sacc[4] = {{0,0,0,0},{0,0,0,0},{0,0,0,0},{0,0,0,0}};
        __builtin_amdgcn_s_setprio(1);
#pragma unroll
        for (int kk = 0; kk < 2; ++kk)
#pragma unroll
            for (int ct = 0; ct < 4; ++ct) {
                bf16x8 af = *(const bf16x8*)(Ks[t & 1] + swz(ct * 16 + c16, kk * 64 + g * 16));
                sacc[ct] = __builtin_amdgcn_mfma_f32_16x16x32_bf16(af, qf[kk], sacc[ct], 0, 0, 0);
            }
        __builtin_amdgcn_s_setprio(0);
#pragma unroll
        for (int ct = 0; ct < 4; ++ct) {
            f32x4 e;
#pragma unroll
            for (int r = 0; r < 4; ++r) {
                float s = m4[ct][r] == 0 ? -10000.0f
                                         : fmaf(sacc[ct][r], 0.125f, b4[ct][r]);
                e[r] = __expf(s);
                rsv[ct] += e[r];
            }
            u32x2 u = { pk2(e[0], e[1]), pk2(e[2], e[3]) };
            *(u32x2*)(Ps + swz(qr, ct * 32 + g * 8)) = u;   // own-wave rows
        }
        // dump Ps -> TILED Ex: wave writes 2KB contiguous per tile
        {
            unsigned short* tp = Exg + tb0 + (size_t)t * TILE + qr * 64;
#pragma unroll
            for (int half = 0; half < 2; ++half) {
                bf16x8 d = *(const bf16x8*)(Ps + swz(qr, half * 64 + g * 16));
                *(bf16x8*)(tp + half * 32 + g * 8) = d;
            }
        }
        writeK(Ks[(t + 1) & 1]);
        issueK(kb + ((t + 2) & 7) * 64);     // wrap: harmless extra reads
        issueMB(kb + ((t + 1) & 7) * 64);
        bar();
    }
    float rs = (rsv[0] + rsv[1]) + (rsv[2] + rsv[3]);
    rs += __shfl_xor(rs, 16);
    rs += __shfl_xor(rs, 32);
    if (g == 0)
        ws[(size_t)ks * BHL + (size_t)(b * Hh + h) * Ll + q0 + qr] = rs;
}

// ===== pass 2: PV + LDS-staged row-linear P dump =====
__global__ __launch_bounds__(256)
void attn_pv2(const float* __restrict__ V, const float* __restrict__ ws,
              float* __restrict__ out)
{
    __shared__ char VTs[2][64 * 128];
    __shared__ char Pst[64 * 512];       // 64 rows x 256 bf16 (4 tiles), 32KB

    const int bid = blockIdx.x;          // 4096 blocks
    const int ks = bid & 3;
    const int b  = (bid >> 2) & 1;
    const int qt = (bid >> 3) & 31;
    const int h  = bid >> 8;
    const int q0 = qt * 64;
    const int kb = ks * 512;             // 8 tiles of 64

    const int tid  = threadIdx.x;
    const int w    = tid >> 6;
    const int lane = tid & 63;
    const int g    = lane >> 4;
    const int c16  = lane & 15;
    const int qr   = w * 16 + c16;

    const float* Vp = V + (size_t)(b * Hh + h) * Ll * Dd;
    float* Op = out + ((size_t)(b * Hh + h) * Ll + q0) * Dd;
    float* Pout = out + OUT_ELEMS + (size_t)(b * Hh + h) * Ll * Ll;
    const unsigned short* Exg = (const unsigned short*)(ws + 4 * (size_t)BHL);
    const size_t tb0 = (((size_t)(b * Hh + h) * 32 + qt) * 32 + (kb >> 6)) * TILE;

    float inv, invO[4];
    {
        size_t idx = (size_t)(b * Hh + h) * Ll + q0 + qr;
        float s = ws[idx] + ws[(size_t)BHL + idx]
                + ws[2 * (size_t)BHL + idx] + ws[3 * (size_t)BHL + idx];
        inv = 1.0f / s;
#pragma unroll
        for (int r = 0; r < 4; ++r) invO[r] = __shfl(inv, g * 4 + r);
    }

    float vreg[16];
    auto issueV = [&](int k0) {
#pragma unroll
        for (int r = 0; r < 4; ++r)
#pragma unroll
            for (int i = 0; i < 4; ++i)
                vreg[r * 4 + i] = Vp[(size_t)(k0 + w * 16 + r * 4 + i) * Dd + lane];
    };
    auto writeV = [&](char* buf) {       // transposed: buf[d][k]
#pragma unroll
        for (int r = 0; r < 4; ++r) {
            u32x2 u = { pk2(vreg[r * 4 + 0], vreg[r * 4 + 1]),
                        pk2(vreg[r * 4 + 2], vreg[r * 4 + 3]) };
            *(u32x2*)(buf + swz(lane, (w * 16 + r * 4) * 2)) = u;
        }
    };

    bf16x8 pa[2];
    auto loadA = [&](int t) {            // P fragments from tiled Ex
        const unsigned short* tp = Exg + tb0 + (size_t)t * TILE + qr * 64;
        pa[0] = *(const bf16x8*)(tp + g * 8);
        pa[1] = *(const bf16x8*)(tp + 32 + g * 8);
    };

    issueV(kb);
    loadA(0);
    writeV(VTs[0]);
    issueV(kb + 64);
    bar();

    f32x4 oacc[4] = {{0,0,0,0},{0,0,0,0},{0,0,0,0},{0,0,0,0}};
    for (int t = 0; t < 8; ++t) {
        __builtin_amdgcn_s_setprio(1);
#pragma unroll
        for (int kk = 0; kk < 2; ++kk)
#pragma unroll
            for (int dt = 0; dt < 4; ++dt) {
                bf16x8 vf = *(const bf16x8*)(VTs[t & 1] + swz(dt * 16 + c16, kk * 64 + g * 16));
                oacc[dt] = __builtin_amdgcn_mfma_f32_16x16x32_bf16(pa[kk], vf, oacc[dt], 0, 0, 0);
            }
        __builtin_amdgcn_s_setprio(0);
        // stash pa into Pstage (wave-private rows; swizzled, 16B stores)
#pragma unroll
        for (int kk = 0; kk < 2; ++kk) {
            int colB = (((t & 3) * 128 + kk * 64 + g * 16)) ^ ((qr & 15) << 4);
            *(bf16x8*)(Pst + qr * 512 + colB) = pa[kk];
        }
        // row-linear P dump every 4 tiles: wave writes 1KB contiguous per row
        if ((t & 3) == 3) {
            const int di = t >> 2;
#pragma unroll
            for (int i = 0; i < 16; ++i) {
                const int row = w * 16 + i;
                const float rinv = __shfl(inv, i);
                const int colB = (lane * 8) ^ (i << 4);   // row&15 == i
                bf16x4 e = *(const bf16x4*)(Pst + row * 512 + colB);
                f32x4 p;
#pragma unroll
                for (int j = 0; j < 4; ++j) p[j] = bf2f(e[j]) * rinv;
                float* dst = Pout + (size_t)(q0 + row) * Ll + kb + di * 256 + lane * 4;
                __builtin_nontemporal_store(p, (f32x4*)dst);
            }
        }
        loadA((t + 1) & 7);              // wrap: harmless
        writeV(VTs[(t + 1) & 1]);
        issueV(kb + ((t + 2) & 7) * 64);
        bar();
    }
    // O: exactly 4 contributions per element (ks=0..3); fp reorder jitter
    // ~1e-6, far below the 2.45e-2 threshold
#pragma unroll
    for (int dt = 0; dt < 4; ++dt)
#pragma unroll
        for (int r = 0; r < 4; ++r)
            unsafeAtomicAdd(&Op[(w * 16 + g * 4 + r) * Dd + dt * 16 + c16],
                            oacc[dt][r] * invO[r]);
}

extern "C" void kernel_launch(void* const* d_in, const int* in_sizes, int n_in,
                              void* d_out, int out_size, void* d_ws, size_t ws_size,
                              hipStream_t stream) {
    const float* Q  = (const float*)d_in[0];
    const float* K  = (const float*)d_in[1];
    const float* V  = (const float*)d_in[2];
    const int*   M  = (const int*)d_in[3];
    const float* Bi = (const float*)d_in[4];
    float* out = (float*)d_out;
    float* ws  = (float*)d_ws;

    // ws layout: [0, 1MB) rowsum partials; [1MB, +268MB) tiled bf16 exp(S)
    const size_t need = 4ull * BHL * sizeof(float)
                      + (size_t)BHL * Ll * sizeof(unsigned short);
    if (ws_size >= need) {
        (void)hipMemsetAsync(out, 0, (size_t)OUT_ELEMS * sizeof(float), stream);
        attn_exp<<<dim3(4096), dim3(256), 0, stream>>>(Q, K, M, Bi, ws);
        attn_pv2<<<dim3(4096), dim3(256), 0, stream>>>(V, ws, out);
    }
}

// Round 15
// 413.685 us; speedup vs baseline: 1.1957x; 1.0061x over previous
//
#include <hip/hip_runtime.h>
#include <hip/hip_bf16.h>

#define Bb 2
#define Hh 16
#define Ll 2048
#define Dd 64
#define OUT_ELEMS (Bb*Hh*Ll*Dd)
#define BHL (Bb*Hh*Ll)
#define TILE 4096   // one Ex tile = 64q x 64k bf16 elements

typedef __attribute__((ext_vector_type(8))) short bf16x8;
typedef __attribute__((ext_vector_type(2))) short bf16x2;
typedef __attribute__((ext_vector_type(4))) float f32x4;
typedef __attribute__((ext_vector_type(2))) float f32x2;
typedef __attribute__((ext_vector_type(4))) int i32x4;
typedef __attribute__((ext_vector_type(2))) unsigned int u32x2;

__device__ __forceinline__ unsigned int pk2(float a, float b) {
    unsigned int r;
    asm("v_cvt_pk_bf16_f32 %0, %1, %2" : "=v"(r) : "v"(a), "v"(b));
    return r;
}
__device__ __forceinline__ float bf2f(short s) {
    union { float f; unsigned u; } c;
    c.u = ((unsigned)(unsigned short)s) << 16;
    return c.f;
}
// raw barrier: does NOT drain vmcnt -> prefetched loads stay in flight (T4)
__device__ __forceinline__ void bar() {
    asm volatile("s_waitcnt lgkmcnt(0)" ::: "memory");
    __builtin_amdgcn_s_barrier();
}
// XOR-swizzled LDS byte offset for 128B rows (kills ds_read_b128 conflicts)
__device__ __forceinline__ int swz(int row, int colByte) {
    return row * 128 + (colByte ^ ((row & 7) << 4));
}

// ===== pass 1: exp(S) -> TILED bf16 scratch + partial rowsums (+O zeroing) =====
__global__ __launch_bounds__(256)
void attn_exp(const float* __restrict__ Q, const float* __restrict__ K,
              const int* __restrict__ M, const float* __restrict__ Bi,
              float* __restrict__ ws, float* __restrict__ out)
{
    __shared__ char Ks[2][64 * 128];
    __shared__ char Ps[64 * 128];

    const int bid = blockIdx.x;          // 4096 blocks
    const int ks = bid & 3;
    const int b  = (bid >> 2) & 1;
    const int qt = (bid >> 3) & 31;
    const int h  = bid >> 8;
    const int q0 = qt * 64;
    const int kb = ks * 512;             // 8 tiles of 64

    const int tid  = threadIdx.x;
    const int w    = tid >> 6;
    const int lane = tid & 63;
    const int g    = lane >> 4;
    const int c16  = lane & 15;
    const int qr   = w * 16 + c16;

    const float* Qp = Q + ((size_t)(b * Hh + h) * Ll + q0) * Dd;
    const float* Kp = K + (size_t)(b * Hh + h) * Ll * Dd;
    const int*   mrow = M  + (size_t)b * Ll * Ll + ((size_t)q0 + qr) * Ll;
    const float* brow = Bi + (size_t)h * Ll * Ll + ((size_t)q0 + qr) * Ll;
    unsigned short* Exg = (unsigned short*)(ws + 4 * (size_t)BHL);
    const size_t tb0 = (((size_t)(b * Hh + h) * 32 + qt) * 32 + (kb >> 6)) * TILE;

    // zero the O tile (atomic target in pass 2; stream order makes it safe)
    if (ks == 0) {
        float* Oz = out + ((size_t)(b * Hh + h) * Ll + q0) * Dd;
        const f32x4 z = {0.f, 0.f, 0.f, 0.f};
#pragma unroll
        for (int r = 0; r < 4; ++r)
            __builtin_nontemporal_store(z, (f32x4*)(Oz + (size_t)(r * 256 + tid) * 4));
    }

    bf16x8 qf[2];
    {
        const float* qrow = Qp + qr * Dd;
#pragma unroll
        for (int kk = 0; kk < 2; ++kk) {
            f32x4 a = *(const f32x4*)(qrow + kk * 32 + g * 8);
            f32x4 c = *(const f32x4*)(qrow + kk * 32 + g * 8 + 4);
            union { bf16x8 v; unsigned int u[4]; } cvt;
            cvt.u[0] = pk2(a[0], a[1]); cvt.u[1] = pk2(a[2], a[3]);
            cvt.u[2] = pk2(c[0], c[1]); cvt.u[3] = pk2(c[2], c[3]);
            qf[kk] = cvt.v;
        }
    }

    float4 kreg[4];
    i32x4  m4[4];
    f32x4  b4[4];
    const int r0 = tid >> 4, d0 = (tid & 15) * 4;

    auto issueK = [&](int k0) {
#pragma unroll
        for (int rep = 0; rep < 4; ++rep)
            kreg[rep] = *(const float4*)(Kp + (size_t)(k0 + r0 + rep * 16) * Dd + d0);
    };
    auto writeK = [&](char* buf) {
#pragma unroll
        for (int rep = 0; rep < 4; ++rep) {
            u32x2 u = { pk2(kreg[rep].x, kreg[rep].y), pk2(kreg[rep].z, kreg[rep].w) };
            *(u32x2*)(buf + swz(r0 + rep * 16, d0 * 2)) = u;
        }
    };
    auto issueMB = [&](int k0) {
#pragma unroll
        for (int ct = 0; ct < 4; ++ct) {
            m4[ct] = *(const i32x4*)(mrow + k0 + ct * 16 + g * 4);
            b4[ct] = *(const f32x4*)(brow + k0 + ct * 16 + g * 4);
        }
    };

    issueK(kb);
    issueMB(kb);
    writeK(Ks[0]);
    issueK(kb + 64);
    bar();

    float rsv[4] = {0.f, 0.f, 0.f, 0.f};
    for (int t = 0; t < 8; ++t) {
        f32x4 sacc[4] = {{0,0,0,0},{0,0,0,0},{0,0,0,0},{0,0,0,0}};
        __builtin_amdgcn_s_setprio(1);
#pragma unroll
        for (int kk = 0; kk < 2; ++kk)
#pragma unroll
            for (int ct = 0; ct < 4; ++ct) {
                bf16x8 af = *(const bf16x8*)(Ks[t & 1] + swz(ct * 16 + c16, kk * 64 + g * 16));
                sacc[ct] = __builtin_amdgcn_mfma_f32_16x16x32_bf16(af, qf[kk], sacc[ct], 0, 0, 0);
            }
        __builtin_amdgcn_s_setprio(0);
#pragma unroll
        for (int ct = 0; ct < 4; ++ct) {
            f32x4 e;
#pragma unroll
            for (int r = 0; r < 4; ++r) {
                float s = m4[ct][r] == 0 ? -10000.0f
                                         : fmaf(sacc[ct][r], 0.125f, b4[ct][r]);
                e[r] = __expf(s);
                rsv[ct] += e[r];
            }
            u32x2 u = { pk2(e[0], e[1]), pk2(e[2], e[3]) };
            *(u32x2*)(Ps + swz(qr, ct * 32 + g * 8)) = u;   // own-wave rows
        }
        // dump Ps -> TILED Ex: wave writes 2KB contiguous per tile
        {
            unsigned short* tp = Exg + tb0 + (size_t)t * TILE + qr * 64;
#pragma unroll
            for (int half = 0; half < 2; ++half) {
                bf16x8 d = *(const bf16x8*)(Ps + swz(qr, half * 64 + g * 16));
                *(bf16x8*)(tp + half * 32 + g * 8) = d;
            }
        }
        writeK(Ks[(t + 1) & 1]);
        issueK(kb + ((t + 2) & 7) * 64);     // wrap: harmless extra reads
        issueMB(kb + ((t + 1) & 7) * 64);
        bar();
    }
    float rs = (rsv[0] + rsv[1]) + (rsv[2] + rsv[3]);
    rs += __shfl_xor(rs, 16);
    rs += __shfl_xor(rs, 32);
    if (g == 0)
        ws[(size_t)ks * BHL + (size_t)(b * Hh + h) * Ll + q0 + qr] = rs;
}

// ===== pass 2: PV + LDS-staged row-linear P dump (32KB LDS -> 5 blocks/CU) =====
__global__ __launch_bounds__(256)
void attn_pv2(const float* __restrict__ V, const float* __restrict__ ws,
              float* __restrict__ out)
{
    __shared__ char VTs[2][64 * 128];
    __shared__ char Pst[64 * 256];       // 64 rows x 128 bf16 (2 tiles), 16KB

    const int bid = blockIdx.x;          // 4096 blocks
    const int ks = bid & 3;
    const int b  = (bid >> 2) & 1;
    const int qt = (bid >> 3) & 31;
    const int h  = bid >> 8;
    const int q0 = qt * 64;
    const int kb = ks * 512;             // 8 tiles of 64

    const int tid  = threadIdx.x;
    const int w    = tid >> 6;
    const int lane = tid & 63;
    const int g    = lane >> 4;
    const int c16  = lane & 15;
    const int qr   = w * 16 + c16;

    const float* Vp = V + (size_t)(b * Hh + h) * Ll * Dd;
    float* Op = out + ((size_t)(b * Hh + h) * Ll + q0) * Dd;
    float* Pout = out + OUT_ELEMS + (size_t)(b * Hh + h) * Ll * Ll;
    const unsigned short* Exg = (const unsigned short*)(ws + 4 * (size_t)BHL);
    const size_t tb0 = (((size_t)(b * Hh + h) * 32 + qt) * 32 + (kb >> 6)) * TILE;

    float inv, invO[4];
    {
        size_t idx = (size_t)(b * Hh + h) * Ll + q0 + qr;
        float s = ws[idx] + ws[(size_t)BHL + idx]
                + ws[2 * (size_t)BHL + idx] + ws[3 * (size_t)BHL + idx];
        inv = 1.0f / s;
#pragma unroll
        for (int r = 0; r < 4; ++r) invO[r] = __shfl(inv, g * 4 + r);
    }

    float vreg[16];
    auto issueV = [&](int k0) {
#pragma unroll
        for (int r = 0; r < 4; ++r)
#pragma unroll
            for (int i = 0; i < 4; ++i)
                vreg[r * 4 + i] = Vp[(size_t)(k0 + w * 16 + r * 4 + i) * Dd + lane];
    };
    auto writeV = [&](char* buf) {       // transposed: buf[d][k]
#pragma unroll
        for (int r = 0; r < 4; ++r) {
            u32x2 u = { pk2(vreg[r * 4 + 0], vreg[r * 4 + 1]),
                        pk2(vreg[r * 4 + 2], vreg[r * 4 + 3]) };
            *(u32x2*)(buf + swz(lane, (w * 16 + r * 4) * 2)) = u;
        }
    };

    bf16x8 pa[2];
    auto loadA = [&](int t) {            // P fragments from tiled Ex
        const unsigned short* tp = Exg + tb0 + (size_t)t * TILE + qr * 64;
        pa[0] = *(const bf16x8*)(tp + g * 8);
        pa[1] = *(const bf16x8*)(tp + 32 + g * 8);
    };

    issueV(kb);
    loadA(0);
    writeV(VTs[0]);
    issueV(kb + 64);
    bar();

    f32x4 oacc[4] = {{0,0,0,0},{0,0,0,0},{0,0,0,0},{0,0,0,0}};
    for (int t = 0; t < 8; ++t) {
        __builtin_amdgcn_s_setprio(1);
#pragma unroll
        for (int kk = 0; kk < 2; ++kk)
#pragma unroll
            for (int dt = 0; dt < 4; ++dt) {
                bf16x8 vf = *(const bf16x8*)(VTs[t & 1] + swz(dt * 16 + c16, kk * 64 + g * 16));
                oacc[dt] = __builtin_amdgcn_mfma_f32_16x16x32_bf16(pa[kk], vf, oacc[dt], 0, 0, 0);
            }
        __builtin_amdgcn_s_setprio(0);
        // stash pa into Pstage (wave-private rows; swizzled, 16B stores)
#pragma unroll
        for (int kk = 0; kk < 2; ++kk) {
            int colB = ((t & 1) * 128 + kk * 64 + g * 16) ^ ((qr & 15) << 4);
            *(bf16x8*)(Pst + qr * 256 + colB) = pa[kk];
        }
        // row-linear P dump every 2 tiles: wave writes 512B contiguous per row
        if (t & 1) {
            const int di = t >> 1;
#pragma unroll
            for (int i = 0; i < 16; ++i) {
                const int row = w * 16 + i;
                const float rinv = __shfl(inv, i);
                const int colB = (lane * 4) ^ (i << 4);   // row&15 == i
                bf16x2 e = *(const bf16x2*)(Pst + row * 256 + colB);
                f32x2 p = { bf2f(e[0]) * rinv, bf2f(e[1]) * rinv };
                float* dst = Pout + (size_t)(q0 + row) * Ll + kb + di * 128 + lane * 2;
                __builtin_nontemporal_store(p, (f32x2*)dst);
            }
        }
        loadA((t + 1) & 7);              // wrap: harmless
        writeV(VTs[(t + 1) & 1]);
        issueV(kb + ((t + 2) & 7) * 64);
        bar();
    }
    // O: exactly 4 contributions per element (ks=0..3); fp reorder jitter
    // ~1e-6, far below the 2.45e-2 threshold
#pragma unroll
    for (int dt = 0; dt < 4; ++dt)
#pragma unroll
        for (int r = 0; r < 4; ++r)
            unsafeAtomicAdd(&Op[(w * 16 + g * 4 + r) * Dd + dt * 16 + c16],
                            oacc[dt][r] * invO[r]);
}

extern "C" void kernel_launch(void* const* d_in, const int* in_sizes, int n_in,
                              void* d_out, int out_size, void* d_ws, size_t ws_size,
                              hipStream_t stream) {
    const float* Q  = (const float*)d_in[0];
    const float* K  = (const float*)d_in[1];
    const float* V  = (const float*)d_in[2];
    const int*   M  = (const int*)d_in[3];
    const float* Bi = (const float*)d_in[4];
    float* out = (float*)d_out;
    float* ws  = (float*)d_ws;

    // ws layout: [0, 1MB) rowsum partials; [1MB, +268MB) tiled bf16 exp(S)
    const size_t need = 4ull * BHL * sizeof(float)
                      + (size_t)BHL * Ll * sizeof(unsigned short);
    if (ws_size >= need) {
        attn_exp<<<dim3(4096), dim3(256), 0, stream>>>(Q, K, M, Bi, ws, out);
        attn_pv2<<<dim3(4096), dim3(256), 0, stream>>>(V, ws, out);
    }
}